// Round 14
// baseline (1854.112 us; speedup 1.0000x reference)
//
#include <hip/hip_runtime.h>

// Problem constants
#define BB 16
#define NN 2048
#define KK 20

#define NEG_INF (-3.402823466e+38f)
#define DNEG (-1.0e300)

// ---------------------------------------------------------------------------
// Weight prep (f32 transposes, used by conv3): offsets in wb:
//   w5lo[64][64]@16768 w5hi[64][64]@20864
// ---------------------------------------------------------------------------
__global__ void prep_wf(const float* __restrict__ w1, const float* __restrict__ w2,
                        const float* __restrict__ w3, const float* __restrict__ w4,
                        const float* __restrict__ w5, float* __restrict__ wb) {
    int t = threadIdx.x;
    for (int i = t; i < 4096; i += 256) {
        int a = i >> 6, q = i & 63;
        wb[16768 + i] = w5[q * 128 + a];       // w5lo[c=a][o=q]
        wb[20864 + i] = w5[q * 128 + 64 + a];  // w5hi[c=a][o=q]
    }
}

// ---------------------------------------------------------------------------
// Composed fp64 weights:
//  M1[3][64]@0  Mh1[3][64]@192  g01[64]@384
//  M2[64][64]@448  Mh2[64][64]@4544  g02[64]@8640     (8704 doubles)
// ---------------------------------------------------------------------------
__global__ void prep_cmp(const float* __restrict__ w1, const float* __restrict__ b1,
                         const float* __restrict__ w2, const float* __restrict__ b2,
                         const float* __restrict__ w3, const float* __restrict__ b3,
                         const float* __restrict__ w4, const float* __restrict__ b4,
                         double* __restrict__ wd2) {
    int t = threadIdx.x;
    for (int i = t; i < 192; i += 256) {
        int c = i >> 6, o = i & 63;
        double s = 0, sh = 0;
        for (int j = 0; j < 64; ++j) {
            double w2v = (double)w2[o * 64 + j];
            s  = fma(w2v, (double)w1[j * 6 + c], s);
            sh = fma(w2v, (double)w1[j * 6 + 3 + c], sh);
        }
        wd2[i] = s;
        wd2[192 + i] = sh;
    }
    for (int i = t; i < 64; i += 256) {
        double s = (double)b2[i];
        for (int j = 0; j < 64; ++j)
            s = fma((double)w2[i * 64 + j], (double)b1[j], s);
        wd2[384 + i] = s;
        double s2 = (double)b4[i];
        for (int j = 0; j < 64; ++j)
            s2 = fma((double)w4[i * 64 + j], (double)b3[j], s2);
        wd2[8640 + i] = s2;
    }
    for (int i = t; i < 4096; i += 256) {
        int c = i >> 6, o = i & 63;
        double s = 0, sh = 0;
        for (int j = 0; j < 64; ++j) {
            double w4v = (double)w4[o * 64 + j];
            s  = fma(w4v, (double)w3[j * 128 + c], s);
            sh = fma(w4v, (double)w3[j * 128 + 64 + c], sh);
        }
        wd2[448 + i] = s;    // M2[c][o]
        wd2[4544 + i] = sh;  // Mh2[c][o]
    }
}

// ---------------------------------------------------------------------------
// Top-20 selection over 2048 f32 candidates in a per-wave LDS row.
// FROZEN: stable ties -> lowest index.
// ---------------------------------------------------------------------------
__device__ __forceinline__ void top2_upd(float v, int g, float& av, int& ai,
                                         float& bv, int& bi) {
    bool gta = v > av;
    bool gtb = v > bv;
    float nbv = gta ? av : (gtb ? v : bv);
    int   nbi = gta ? ai : (gtb ? g : bi);
    av = gta ? v : av;
    ai = gta ? g : ai;
    bv = nbv;
    bi = nbi;
}

__device__ __forceinline__ void topk20_run(float* vrow, int lane, float av, int ai,
                                           float bv, int bi, int* outp) {
    int myout = 0;
    #pragma unroll 1
    for (int it = 0; it < 20; ++it) {
        float wv = av;
        #pragma unroll
        for (int d = 32; d; d >>= 1) wv = fmaxf(wv, __shfl_xor(wv, d));
        unsigned long long bal = __ballot(av == wv);
        int widx;
        if (__popcll(bal) == 1) {
            widx = __shfl(ai, __ffsll(bal) - 1);
        } else {  // exact tie across lanes: lowest global index wins
            int tt = (av == wv) ? ai : 0x7fffffff;
            #pragma unroll
            for (int d = 32; d; d >>= 1) tt = min(tt, __shfl_xor(tt, d));
            widx = tt;
        }
        if (lane == it) myout = widx;
        if (lane == 0) vrow[widx] = NEG_INF;   // remove winner
        if (ai == widx) { av = bv; ai = bi; bv = NEG_INF; bi = 0x7fffffff; }
        if (av == NEG_INF) {                   // rare: lane's top-2 exhausted
            ai = 0x7fffffff; bv = NEG_INF; bi = 0x7fffffff;
            #pragma unroll 1
            for (int s = 0; s < 32; ++s) {
                int col = s * 64 + lane;
                top2_upd(vrow[col], col, av, ai, bv, bi);
            }
        }
    }
    if (lane < 20) outp[lane] = myout;
}

// ---------------------------------------------------------------------------
// knn1: numpy-f32 mirror, FROZEN arithmetic.
// ---------------------------------------------------------------------------
__global__ void knn1_k(const float* __restrict__ x, int* __restrict__ idx) {
    __shared__ float vlds[2][2048];
    int lane = threadIdx.x & 63, w = threadIdx.x >> 6;
    int b = blockIdx.y, r = blockIdx.x * 2 + w;
    const float* xb = x + (size_t)b * 3 * NN;
    float rx = xb[r], ry = xb[NN + r], rz = xb[2 * NN + r];
    float xxi = __fadd_rn(__fadd_rn(__fmul_rn(rx, rx), __fmul_rn(ry, ry)),
                          __fmul_rn(rz, rz));
    float* vrow = vlds[w];
    float av = NEG_INF, bv = NEG_INF;
    int ai = 0x7fffffff, bi = 0x7fffffff;
    #pragma unroll 1
    for (int s = 0; s < 32; ++s) {
        int col = s * 64 + lane;
        float cx = xb[col], cy = xb[NN + col], cz = xb[2 * NN + col];
        float xxj = __fadd_rn(__fadd_rn(__fmul_rn(cx, cx), __fmul_rn(cy, cy)),
                              __fmul_rn(cz, cz));
        float dot = fmaf(rz, cz, fmaf(ry, cy, __fmul_rn(rx, cx)));
        float inner = __fmul_rn(-2.f, dot);
        float t1 = __fsub_rn(-xxj, inner);
        float nd = __fsub_rn(t1, xxi);
        vrow[col] = nd;
        top2_upd(nd, col, av, ai, bv, bi);
    }
    topk20_run(vrow, lane, av, ai, bv, bi, idx + ((size_t)b * NN + r) * KK);
}

// xx for a 64-channel slice. FROZEN.
__global__ void norms23_k(const float* __restrict__ x123t, int coff,
                          float* __restrict__ nrm) {
    int t = blockIdx.x * 256 + threadIdx.x;   // 32768 points
    const float* r = x123t + (size_t)t * 192 + coff;
    float acc = 0.f;
    #pragma unroll 1
    for (int c = 0; c < 64; ++c)
        acc = __fadd_rn(acc, __fmul_rn(r[c], r[c]));
    nrm[t] = acc;
}

// ---------------------------------------------------------------------------
// pd GEMM (knn2/3 distances): 64x64 output tile per block, K=64 single tile.
// Each acc[i][j] gets one fmaf per ascending c  -> FROZEN chain preserved.
// Epilogue: frozen inner/t1/nd sequence. Inputs from channel-major dout slab.
// ---------------------------------------------------------------------------
__global__ __launch_bounds__(256) void gemm_pd_k(const float* __restrict__ dout,
        int coff, const float* __restrict__ nrm, float* __restrict__ pd, int b0) {
    __shared__ float As[64][68];
    __shared__ float Bs[64][68];
    int b = b0 + blockIdx.z;
    int rb = blockIdx.y * 64, cb = blockIdx.x * 64;
    const float* doutc = dout + (size_t)(b * 192 + coff) * NN;
    int tid = threadIdx.x;
    int cq = tid >> 4, qd = (tid & 15) * 4;
    #pragma unroll
    for (int cc = 0; cc < 64; cc += 16) {
        float4 a = *(const float4*)(doutc + (size_t)(cc + cq) * NN + rb + qd);
        As[cc + cq][qd + 0] = a.x; As[cc + cq][qd + 1] = a.y;
        As[cc + cq][qd + 2] = a.z; As[cc + cq][qd + 3] = a.w;
        float4 bv = *(const float4*)(doutc + (size_t)(cc + cq) * NN + cb + qd);
        Bs[cc + cq][qd + 0] = bv.x; Bs[cc + cq][qd + 1] = bv.y;
        Bs[cc + cq][qd + 2] = bv.z; Bs[cc + cq][qd + 3] = bv.w;
    }
    __syncthreads();
    int tx = tid & 15, ty = tid >> 4;
    float acc[4][4];
    #pragma unroll
    for (int i = 0; i < 4; ++i)
        #pragma unroll
        for (int j = 0; j < 4; ++j) acc[i][j] = 0.f;
    #pragma unroll 4
    for (int c = 0; c < 64; ++c) {
        float4 av4 = *(const float4*)&As[c][ty * 4];
        float4 bv4 = *(const float4*)&Bs[c][tx * 4];
        float aa[4] = {av4.x, av4.y, av4.z, av4.w};
        float bb[4] = {bv4.x, bv4.y, bv4.z, bv4.w};
        #pragma unroll
        for (int i = 0; i < 4; ++i)
            #pragma unroll
            for (int j = 0; j < 4; ++j)
                acc[i][j] = fmaf(aa[i], bb[j], acc[i][j]);  // ascending-c chain
    }
    const float* nb_ = nrm + (size_t)b * NN;
    #pragma unroll
    for (int i = 0; i < 4; ++i) {
        int r = rb + ty * 4 + i;
        float xxi = nb_[r];
        float4 o4;
        float* o = (float*)&o4;
        #pragma unroll
        for (int j = 0; j < 4; ++j) {
            float xxj = nb_[cb + tx * 4 + j];
            float inner = __fmul_rn(-2.f, acc[i][j]);
            float t1 = __fsub_rn(-xxj, inner);
            o[j] = __fsub_rn(t1, xxi);
        }
        *(float4*)(pd + ((size_t)blockIdx.z * NN + r) * NN + cb + tx * 4) = o4;
    }
}

// selection from materialized pd chunk (same frozen helpers as knn1)
__global__ void select_k(const float* __restrict__ pd, int* __restrict__ idx, int b0) {
    __shared__ float vlds[4][2048];
    int lane = threadIdx.x & 63, w = threadIdx.x >> 6;
    int bb = blockIdx.y, r = blockIdx.x * 4 + w;
    const float* row = pd + ((size_t)bb * NN + r) * NN;
    float* vrow = vlds[w];
    float av = NEG_INF, bv = NEG_INF;
    int ai = 0x7fffffff, bi = 0x7fffffff;
    #pragma unroll 1
    for (int s = 0; s < 32; ++s) {
        int col = s * 64 + lane;
        float v = row[col];
        vrow[col] = v;
        top2_upd(v, col, av, ai, bv, bi);
    }
    topk20_run(vrow, lane, av, ai, bv, bi, idx + ((size_t)(b0 + bb) * NN + r) * KK);
}

// ---------------------------------------------------------------------------
// EdgeConv blocks with composed fp64 weights + neighbor prefetch.
// conv2/conv3: 512 threads (8 waves) per block for occupancy.
// ---------------------------------------------------------------------------
__global__ __launch_bounds__(256) void conv1_k(const float* __restrict__ x,
        const int* __restrict__ idxb, const double* __restrict__ wd2,
        float* __restrict__ dout, float* __restrict__ x123t) {
    int tid = threadIdx.x, lane = tid & 63, w = tid >> 6;
    int p = blockIdx.x * 4 + w, b = p >> 11, n = p & 2047;
    const float* xb = x + (size_t)b * 3 * NN;
    double c0 = (double)xb[n], c1 = (double)xb[NN + n], c2 = (double)xb[2 * NN + n];
    double m10 = wd2[lane], m11 = wd2[64 + lane], m12 = wd2[128 + lane];
    double g = wd2[384 + lane];
    g = fma(wd2[192 + lane], c0, g);
    g = fma(wd2[256 + lane], c1, g);
    g = fma(wd2[320 + lane], c2, g);
    const int* ip = idxb + (size_t)p * KK;
    int nb = ip[0];
    float f0 = xb[nb], f1 = xb[NN + nb], f2 = xb[2 * NN + nb];
    double m = DNEG;
    #pragma unroll 1
    for (int kk = 0; kk < KK; ++kk) {
        double d0 = (double)f0 - c0, d1 = (double)f1 - c1, d2 = (double)f2 - c2;
        if (kk < KK - 1) {
            int nb2 = ip[kk + 1];
            f0 = xb[nb2]; f1 = xb[NN + nb2]; f2 = xb[2 * NN + nb2];
        }
        double h = g;
        h = fma(m10, d0, h);
        h = fma(m11, d1, h);
        h = fma(m12, d2, h);
        m = fmax(m, h);
    }
    dout[((size_t)b * 192 + lane) * NN + n] = (float)m;
    x123t[((size_t)b * NN + n) * 192 + lane] = (float)m;
}

__global__ __launch_bounds__(512) void conv2_k(const float* __restrict__ x123t,
        const int* __restrict__ idxb, const double* __restrict__ wd2,
        float* __restrict__ dout, float* __restrict__ x123t_o) {
    __shared__ double M2s[4096];   // 32 KB
    __shared__ double dbs[8][64];  // 4 KB
    int tid = threadIdx.x, lane = tid & 63, w = tid >> 6;
    for (int i = tid; i < 4096; i += 512) M2s[i] = wd2[448 + i];
    __syncthreads();
    int p = blockIdx.x * 8 + w, b = p >> 11, n = p & 2047;
    const float* base = x123t + (size_t)b * NN * 192;
    double ctr = (double)base[(size_t)n * 192 + lane];
    dbs[w][lane] = ctr;
    double g = wd2[8640 + lane];
    #pragma unroll 4
    for (int c = 0; c < 64; ++c)
        g = fma(wd2[4544 + c * 64 + lane], dbs[w][c], g);
    const int* ip = idxb + (size_t)p * KK;
    int nb = ip[0];
    float nbreg = base[(size_t)nb * 192 + lane];
    double m = DNEG;
    #pragma unroll 1
    for (int kk = 0; kk < KK; ++kk) {
        dbs[w][lane] = (double)nbreg - ctr;
        if (kk < KK - 1) {
            int nb2 = ip[kk + 1];
            nbreg = base[(size_t)nb2 * 192 + lane];
        }
        double a0 = g, a1 = 0, a2 = 0, a3 = 0;
        #pragma unroll
        for (int c = 0; c < 64; c += 4) {
            a0 = fma(M2s[(c + 0) * 64 + lane], dbs[w][c + 0], a0);
            a1 = fma(M2s[(c + 1) * 64 + lane], dbs[w][c + 1], a1);
            a2 = fma(M2s[(c + 2) * 64 + lane], dbs[w][c + 2], a2);
            a3 = fma(M2s[(c + 3) * 64 + lane], dbs[w][c + 3], a3);
        }
        m = fmax(m, (a0 + a1) + (a2 + a3));
    }
    dout[((size_t)b * 192 + 64 + lane) * NN + n] = (float)m;
    x123t_o[((size_t)b * NN + n) * 192 + 64 + lane] = (float)m;
}

__global__ __launch_bounds__(512) void conv3_k(const float* __restrict__ x123t,
        const int* __restrict__ idxb, const float* __restrict__ wb,
        const float* __restrict__ b5,
        float* __restrict__ dout, float* __restrict__ x123t_o) {
    __shared__ float w5s[4096];    // 16 KB
    __shared__ double dbs[8][64];  // 4 KB
    int tid = threadIdx.x, lane = tid & 63, w = tid >> 6;
    for (int i = tid; i < 4096; i += 512) w5s[i] = wb[16768 + i];
    __syncthreads();
    int p = blockIdx.x * 8 + w, b = p >> 11, n = p & 2047;
    const float* base = x123t + (size_t)b * NN * 192 + 64;  // x2 slice
    double ctr = (double)base[(size_t)n * 192 + lane];
    dbs[w][lane] = ctr;
    double h0 = (double)b5[lane], h1a = 0, h2a = 0, h3a = 0;
    #pragma unroll 4
    for (int c = 0; c < 64; c += 4) {
        h0  = fma((double)wb[20864 + (c + 0) * 64 + lane], dbs[w][c + 0], h0);
        h1a = fma((double)wb[20864 + (c + 1) * 64 + lane], dbs[w][c + 1], h1a);
        h2a = fma((double)wb[20864 + (c + 2) * 64 + lane], dbs[w][c + 2], h2a);
        h3a = fma((double)wb[20864 + (c + 3) * 64 + lane], dbs[w][c + 3], h3a);
    }
    double hc = (h0 + h1a) + (h2a + h3a);
    const int* ip = idxb + (size_t)p * KK;
    int nb = ip[0];
    float nbreg = base[(size_t)nb * 192 + lane];
    double m = DNEG;
    #pragma unroll 1
    for (int kk = 0; kk < KK; ++kk) {
        dbs[w][lane] = (double)nbreg - ctr;
        if (kk < KK - 1) {
            int nb2 = ip[kk + 1];
            nbreg = base[(size_t)nb2 * 192 + lane];
        }
        double a0 = hc, a1 = 0, a2 = 0, a3 = 0;
        #pragma unroll
        for (int c = 0; c < 64; c += 4) {
            a0 = fma((double)w5s[(c + 0) * 64 + lane], dbs[w][c + 0], a0);
            a1 = fma((double)w5s[(c + 1) * 64 + lane], dbs[w][c + 1], a1);
            a2 = fma((double)w5s[(c + 2) * 64 + lane], dbs[w][c + 2], a2);
            a3 = fma((double)w5s[(c + 3) * 64 + lane], dbs[w][c + 3], a3);
        }
        m = fmax(m, (a0 + a1) + (a2 + a3));
    }
    dout[((size_t)b * 192 + 128 + lane) * NN + n] = (float)m;
    x123t_o[((size_t)b * NN + n) * 192 + 128 + lane] = (float)m;
}

// ---------------------------------------------------------------------------
// Final conv1d (1024x192) as LDS-tiled f32 GEMM, 64o x 64n per block, KC=32.
// ---------------------------------------------------------------------------
#define KC 32
__global__ __launch_bounds__(256) void w6_k(const float* __restrict__ x123t,
                                            const float* __restrict__ w6,
                                            float* __restrict__ partial6) {
    __shared__ float xs[KC][68];
    __shared__ float wsb[KC][68];
    __shared__ float red[64][17];
    int tid = threadIdx.x;
    int ntile = blockIdx.x & 31, ot = (blockIdx.x >> 5) & 15, b = blockIdx.x >> 9;
    int n0 = ntile * 64, o0 = ot * 64;
    int ln = tid >> 2, lc = (tid & 3) * 8;
    const float* xrow = x123t + ((size_t)b * NN + n0 + ln) * 192 + lc;
    const float* wrow = w6 + (size_t)(o0 + ln) * 192 + lc;
    float acc[4][4];
    #pragma unroll
    for (int i = 0; i < 4; ++i)
        #pragma unroll
        for (int j = 0; j < 4; ++j) acc[i][j] = 0.f;
    int to = tid & 15, tn = tid >> 4;
    for (int cc = 0; cc < 192; cc += KC) {
        float4 xa = *(const float4*)(xrow + cc);
        float4 xb4 = *(const float4*)(xrow + cc + 4);
        float4 wa = *(const float4*)(wrow + cc);
        float4 wb4 = *(const float4*)(wrow + cc + 4);
        __syncthreads();
        xs[lc + 0][ln] = xa.x; xs[lc + 1][ln] = xa.y;
        xs[lc + 2][ln] = xa.z; xs[lc + 3][ln] = xa.w;
        xs[lc + 4][ln] = xb4.x; xs[lc + 5][ln] = xb4.y;
        xs[lc + 6][ln] = xb4.z; xs[lc + 7][ln] = xb4.w;
        wsb[lc + 0][ln] = wa.x; wsb[lc + 1][ln] = wa.y;
        wsb[lc + 2][ln] = wa.z; wsb[lc + 3][ln] = wa.w;
        wsb[lc + 4][ln] = wb4.x; wsb[lc + 5][ln] = wb4.y;
        wsb[lc + 6][ln] = wb4.z; wsb[lc + 7][ln] = wb4.w;
        __syncthreads();
        #pragma unroll
        for (int k = 0; k < KC; ++k) {
            float4 wv = *(const float4*)&wsb[k][to * 4];
            float4 xv = *(const float4*)&xs[k][tn * 4];
            float wr[4] = {wv.x, wv.y, wv.z, wv.w};
            float xr[4] = {xv.x, xv.y, xv.z, xv.w};
            #pragma unroll
            for (int i = 0; i < 4; ++i)
                #pragma unroll
                for (int j = 0; j < 4; ++j)
                    acc[i][j] = fmaf(wr[i], xr[j], acc[i][j]);
        }
    }
    #pragma unroll
    for (int i = 0; i < 4; ++i) {
        float mm = fmaxf(fmaxf(acc[i][0], acc[i][1]), fmaxf(acc[i][2], acc[i][3]));
        red[to * 4 + i][tn] = mm;
    }
    __syncthreads();
    if (tid < 64) {
        float mm = red[tid][0];
        #pragma unroll
        for (int t = 1; t < 16; ++t) mm = fmaxf(mm, red[tid][t]);
        partial6[((size_t)b * 1024 + o0 + tid) * 32 + ntile] = mm;
    }
}

__global__ void final_k(const float* __restrict__ partial6, const float* __restrict__ b6,
                        float* __restrict__ dout) {
    int t = blockIdx.x * 256 + threadIdx.x;  // < 16*1024
    int o = t & 1023;
    float m = NEG_INF;
    #pragma unroll 1
    for (int nt = 0; nt < 32; ++nt) m = fmaxf(m, partial6[(size_t)t * 32 + nt]);
    dout[(size_t)BB * 192 * NN + t] = m + b6[o];
}

// ---------------------------------------------------------------------------
extern "C" void kernel_launch(void* const* d_in, const int* in_sizes, int n_in,
                              void* d_out_, int out_size, void* d_ws, size_t ws_size,
                              hipStream_t stream) {
    (void)in_sizes; (void)n_in; (void)out_size;
    const float* x  = (const float*)d_in[0];
    const float* w1 = (const float*)d_in[1];
    const float* b1 = (const float*)d_in[2];
    const float* w2 = (const float*)d_in[3];
    const float* b2 = (const float*)d_in[4];
    const float* w3 = (const float*)d_in[5];
    const float* b3 = (const float*)d_in[6];
    const float* w4 = (const float*)d_in[7];
    const float* b4 = (const float*)d_in[8];
    const float* w5 = (const float*)d_in[9];
    const float* b5 = (const float*)d_in[10];
    const float* w6 = (const float*)d_in[11];
    const float* b6 = (const float*)d_in[12];
    float* dout = (float*)d_out_;

    char* ws = (char*)d_ws;
    float*  x123t    = (float*)(ws + 0);           // 25,165,824 B
    int*    idxb     = (int*)(ws + 25165824);      //  2,621,440 B
    float*  wbuf     = (float*)(ws + 27787264);    //     99,840 B
    float*  nrm      = (float*)(ws + 27887104);    //    131,072 B
    float*  partial6 = (float*)(ws + 28018176);    //  2,097,152 B
    double* wd2      = (double*)(ws + 30115328);   //     69,632 B
    float*  pd       = (float*)(ws + 30212096);    //  nb * 16 MiB
    long long avail = (long long)ws_size - 30212096LL;
    int nb = (int)(avail / 16777216LL);
    if (nb < 1) nb = 1;
    if (nb > 4) nb = 4;   // 64 MB chunks: keep pd L3-resident between gemm & select

    prep_wf<<<1, 256, 0, stream>>>(w1, w2, w3, w4, w5, wbuf);
    prep_cmp<<<1, 256, 0, stream>>>(w1, b1, w2, b2, w3, b3, w4, b4, wd2);

    // ---- block 1 ----
    knn1_k<<<dim3(1024, BB), 128, 0, stream>>>(x, idxb);
    conv1_k<<<8192, 256, 0, stream>>>(x, idxb, wd2, dout, x123t);

    // ---- knn on x1 (tiled GEMM + select, frozen arithmetic) ----
    norms23_k<<<128, 256, 0, stream>>>(x123t, 0, nrm);
    for (int b0 = 0; b0 < BB; b0 += nb) {
        int cur = (BB - b0 < nb) ? (BB - b0) : nb;
        gemm_pd_k<<<dim3(32, 32, cur), 256, 0, stream>>>(dout, 0, nrm, pd, b0);
        select_k<<<dim3(512, cur), 256, 0, stream>>>(pd, idxb, b0);
    }
    conv2_k<<<4096, 512, 0, stream>>>(x123t, idxb, wd2, dout, x123t);

    // ---- knn on x2 ----
    norms23_k<<<128, 256, 0, stream>>>(x123t, 64, nrm);
    for (int b0 = 0; b0 < BB; b0 += nb) {
        int cur = (BB - b0 < nb) ? (BB - b0) : nb;
        gemm_pd_k<<<dim3(32, 32, cur), 256, 0, stream>>>(dout, 64, nrm, pd, b0);
        select_k<<<dim3(512, cur), 256, 0, stream>>>(pd, idxb, b0);
    }
    conv3_k<<<4096, 512, 0, stream>>>(x123t, idxb, wbuf, b5, dout, x123t);

    // ---- final conv1d + global max ----
    w6_k<<<8192, 256, 0, stream>>>(x123t, w6, partial6);
    final_k<<<64, 256, 0, stream>>>(partial6, b6, dout);
}